// Round 1
// baseline (510.035 us; speedup 1.0000x reference)
//
#include <hip/hip_runtime.h>
#include <math.h>

#define B_ 16
#define A_ 256
#define N_ 64
#define G_ 64
#define F_ 128

__device__ __forceinline__ float ssp(float x) {
    // shifted softplus: ln(1+e^x) - ln2, numerically stable
    return fmaxf(x, 0.0f) + log1pf(expf(-fabsf(x))) - 0.69314718055994531f;
}

// Kernel 1: y_pre[b,a,f] = sum_d x[b,a,d] * w_in2f[d,f]
__global__ __launch_bounds__(256) void in2f_kernel(
    const float* __restrict__ x, const float* __restrict__ w,
    float* __restrict__ y)
{
    __shared__ float xs[2][F_];
    const int row0 = blockIdx.x * 2;
    const int tid = threadIdx.x;
    const int r = tid >> 7, f = tid & 127;
    xs[r][f] = x[(size_t)(row0 + r) * F_ + f];
    __syncthreads();
    float acc = 0.0f;
    const float* xrow = xs[r];
    #pragma unroll 8
    for (int k = 0; k < F_; ++k)
        acc = fmaf(xrow[k], w[k * F_ + f], acc);
    y[(size_t)(row0 + r) * F_ + f] = acc;
}

// Kernel 2: one block per (b,a). Filter net + cutoff + gather + aggregate + f2out.
__global__ __launch_bounds__(256) void cfconv_kernel(
    const float* __restrict__ r_ij, const float* __restrict__ f_ij,
    const int*   __restrict__ nbrs, const float* __restrict__ mask,
    const float* __restrict__ fw1,  const float* __restrict__ fb1,
    const float* __restrict__ fw2,  const float* __restrict__ fb2,
    const float* __restrict__ ypre, const float* __restrict__ wf2out,
    const float* __restrict__ bf2out, float* __restrict__ out)
{
    __shared__ float s_fij[N_ * G_];   // 16 KB  [n][g]
    __shared__ float s_h1[N_ * F_];    // 32 KB  [n][f]
    __shared__ float s_scale[N_];
    __shared__ int   s_nb[N_];
    __shared__ float s_red[4][F_];     // 2 KB
    __shared__ float s_yf[F_];

    const int blk = blockIdx.x;        // = b*A + a
    const int tid = threadIdx.x;
    const int b = blk >> 8;            // A = 256

    // stage f_ij tile
    const float* fij_base = f_ij + (size_t)blk * (N_ * G_);
    for (int i = tid; i < N_ * G_; i += 256) s_fij[i] = fij_base[i];

    // cutoff * mask, neighbor indices
    if (tid < N_) {
        const float r = r_ij[(size_t)blk * N_ + tid];
        const float c = (r < 5.0f)
            ? 0.5f * (cosf(r * 0.62831853071795865f) + 1.0f)  // pi/5
            : 0.0f;
        s_scale[tid] = c * mask[(size_t)blk * N_ + tid];
        s_nb[tid] = nbrs[(size_t)blk * N_ + tid];
    }
    __syncthreads();

    // thread owns f in {f0, f0+1}, n in [nh*16, nh*16+16)
    const int fi = tid & 63;
    const int f0 = fi * 2;
    const int nh = tid >> 6;           // wave-uniform

    // ---- step 2: h1 = ssp(f_ij @ fw1 + fb1) ----
    const float b10 = fb1[f0], b11 = fb1[f0 + 1];
    for (int nbk = 0; nbk < 4; ++nbk) {
        const int n0 = nh * 16 + nbk * 4;
        float acc[4][2];
        #pragma unroll
        for (int j = 0; j < 4; ++j) { acc[j][0] = b10; acc[j][1] = b11; }
        #pragma unroll 4
        for (int g = 0; g < G_; ++g) {
            const float2 w = *(const float2*)(fw1 + g * F_ + f0);
            #pragma unroll
            for (int j = 0; j < 4; ++j) {
                const float h = s_fij[(n0 + j) * G_ + g];  // broadcast
                acc[j][0] = fmaf(h, w.x, acc[j][0]);
                acc[j][1] = fmaf(h, w.y, acc[j][1]);
            }
        }
        #pragma unroll
        for (int j = 0; j < 4; ++j) {
            s_h1[(n0 + j) * F_ + f0]     = ssp(acc[j][0]);
            s_h1[(n0 + j) * F_ + f0 + 1] = ssp(acc[j][1]);
        }
    }
    __syncthreads();

    // ---- step 3+4: W = h1@fw2 + fb2, scale by cutoff*mask, gather y, aggregate ----
    const float b20 = fb2[f0], b21 = fb2[f0 + 1];
    const float* yb = ypre + (size_t)b * (A_ * F_);
    float accy0 = 0.0f, accy1 = 0.0f;
    for (int nbk = 0; nbk < 4; ++nbk) {
        const int n0 = nh * 16 + nbk * 4;
        float acc[4][2];
        #pragma unroll
        for (int j = 0; j < 4; ++j) { acc[j][0] = b20; acc[j][1] = b21; }
        #pragma unroll 4
        for (int k = 0; k < F_; ++k) {
            const float2 w = *(const float2*)(fw2 + k * F_ + f0);
            #pragma unroll
            for (int j = 0; j < 4; ++j) {
                const float h = s_h1[(n0 + j) * F_ + k];   // broadcast
                acc[j][0] = fmaf(h, w.x, acc[j][0]);
                acc[j][1] = fmaf(h, w.y, acc[j][1]);
            }
        }
        #pragma unroll
        for (int j = 0; j < 4; ++j) {
            const int n = n0 + j;
            const float sc = s_scale[n];
            const float2 yv = *(const float2*)(yb + (size_t)s_nb[n] * F_ + f0);
            accy0 = fmaf(acc[j][0] * sc, yv.x, accy0);
            accy1 = fmaf(acc[j][1] * sc, yv.y, accy1);
        }
    }
    s_red[nh][f0]     = accy0;
    s_red[nh][f0 + 1] = accy1;
    __syncthreads();

    // ---- reduce across the 4 n-quarters ----
    if (tid < F_) {
        s_yf[tid] = s_red[0][tid] + s_red[1][tid] + s_red[2][tid] + s_red[3][tid];
    }
    __syncthreads();

    // ---- step 5: out = ssp(y @ w_f2out + b_f2out) ----
    if (tid < F_) {
        float acc = bf2out[tid];
        #pragma unroll 8
        for (int k = 0; k < F_; ++k)
            acc = fmaf(s_yf[k], wf2out[k * F_ + tid], acc);
        out[(size_t)blk * F_ + tid] = ssp(acc);
    }
}

extern "C" void kernel_launch(void* const* d_in, const int* in_sizes, int n_in,
                              void* d_out, int out_size, void* d_ws, size_t ws_size,
                              hipStream_t stream) {
    const float* x        = (const float*)d_in[0];
    const float* r_ij     = (const float*)d_in[1];
    const float* f_ij     = (const float*)d_in[2];
    const int*   nbrs     = (const int*)  d_in[3];
    const float* mask     = (const float*)d_in[4];
    const float* fw1      = (const float*)d_in[5];
    const float* fb1      = (const float*)d_in[6];
    const float* fw2      = (const float*)d_in[7];
    const float* fb2      = (const float*)d_in[8];
    const float* w_in2f   = (const float*)d_in[9];
    const float* w_f2out  = (const float*)d_in[10];
    const float* b_f2out  = (const float*)d_in[11];
    float* out = (float*)d_out;
    float* ypre = (float*)d_ws;   // [B,A,F] fp32 = 2 MB

    in2f_kernel<<<B_ * A_ / 2, 256, 0, stream>>>(x, w_in2f, ypre);
    cfconv_kernel<<<B_ * A_, 256, 0, stream>>>(
        r_ij, f_ij, nbrs, mask, fw1, fb1, fw2, fb2,
        ypre, w_f2out, b_f2out, out);
}

// Round 2
// 223.040 us; speedup vs baseline: 2.2867x; 2.2867x over previous
//
#include <hip/hip_runtime.h>
#include <hip/hip_bf16.h>
#include <math.h>

#define B_ 16
#define A_ 256
#define N_ 64
#define G_ 64
#define F_ 128

typedef __attribute__((ext_vector_type(8))) short short8;
typedef __attribute__((ext_vector_type(4))) float floatx4;

__device__ __forceinline__ float ssp(float x) {
    // shifted softplus: ln(1+e^x) - ln2, numerically stable
    return fmaxf(x, 0.0f) + log1pf(expf(-fabsf(x))) - 0.69314718055994531f;
}
__device__ __forceinline__ short f2bf(float f) {
    union { __hip_bfloat16 h; short s; } u;
    u.h = __float2bfloat16(f);
    return u.s;
}
__device__ __forceinline__ float bf2f(unsigned short u) {
    union { unsigned int i; float f; } v;
    v.i = ((unsigned)u) << 16;
    return v.f;
}

// ---------------------------------------------------------------------------
// Kernel 1: ypre[b,a,f] = bf16( sum_d x[b,a,d] * w_in2f[d,f] )
__global__ __launch_bounds__(256) void in2f_kernel(
    const float* __restrict__ x, const float* __restrict__ w,
    unsigned short* __restrict__ y)
{
    __shared__ float xs[2][F_];
    const int row0 = blockIdx.x * 2;
    const int tid = threadIdx.x;
    const int r = tid >> 7, f = tid & 127;
    xs[r][f] = x[(size_t)(row0 + r) * F_ + f];
    __syncthreads();
    float acc = 0.0f;
    const float* xrow = xs[r];
    #pragma unroll 8
    for (int k = 0; k < F_; ++k)
        acc = fmaf(xrow[k], w[k * F_ + f], acc);
    y[(size_t)(row0 + r) * F_ + f] = (unsigned short)f2bf(acc);
}

// ---------------------------------------------------------------------------
// Kernel 2: repack fw1/fw2 into MFMA B-fragment order (bf16).
// fw1B layout: [tf(8)][ks(2)][lane(64)][j(8)]  element = fw1[g][f],
//   g = ks*32 + (lane>>4)*8 + j,  f = tf*16 + (lane&15)
// fw2B layout: [tf(8)][ks(4)][lane(64)][j(8)]  element = fw2[k][f]
__global__ __launch_bounds__(256) void prep_weights(
    const float* __restrict__ fw1, const float* __restrict__ fw2,
    unsigned short* __restrict__ fw1B, unsigned short* __restrict__ fw2B)
{
    const int idx = blockIdx.x * 256 + threadIdx.x;   // 0 .. 24575
    if (idx < 8192) {
        const int j  = idx & 7;
        const int l  = (idx >> 3) & 63;
        const int ks = (idx >> 9) & 1;
        const int tf = idx >> 10;
        const int g  = ks * 32 + (l >> 4) * 8 + j;
        const int f  = tf * 16 + (l & 15);
        fw1B[idx] = (unsigned short)f2bf(fw1[g * F_ + f]);
    } else {
        const int i2 = idx - 8192;                    // 0 .. 16383
        const int j  = i2 & 7;
        const int l  = (i2 >> 3) & 63;
        const int ks = (i2 >> 9) & 3;
        const int tf = i2 >> 11;
        const int k  = ks * 32 + (l >> 4) * 8 + j;
        const int f  = tf * 16 + (l & 15);
        fw2B[i2] = (unsigned short)f2bf(fw2[k * F_ + f]);
    }
}

// ---------------------------------------------------------------------------
// Kernel 3: one block per (b,a). MFMA filter net + cutoff + gather + aggregate
// + f2out. 4 waves; wave w owns neighbor rows [w*16, w*16+16) end-to-end, so
// the main body needs no __syncthreads.
__global__ __launch_bounds__(256) void cfconv_kernel(
    const float* __restrict__ r_ij, const float* __restrict__ f_ij,
    const int*   __restrict__ nbrs, const float* __restrict__ mask,
    const float* __restrict__ fb1,  const float* __restrict__ fb2,
    const unsigned short* __restrict__ ypre,
    const unsigned short* __restrict__ fw1B,
    const unsigned short* __restrict__ fw2B,
    const float* __restrict__ wf2out, const float* __restrict__ bf2out,
    float* __restrict__ out)
{
    __shared__ short s_h1[N_ * F_];    // 16 KB, XOR-swizzled 8-elem chunks
    __shared__ float s_scale[N_];
    __shared__ int   s_nb[N_];
    __shared__ float s_red[4][F_];
    __shared__ float s_yf[F_];

    const int blk  = blockIdx.x;       // b*A + a
    const int tid  = threadIdx.x;
    const int b    = blk >> 8;         // A = 256
    const int w    = tid >> 6;         // wave id 0..3
    const int l    = tid & 63;         // lane
    const int quad = l >> 4;
    const int c0   = l & 15;

    // per-wave cutoff*mask and neighbor idx for this wave's 16 rows
    if (l < 16) {
        const int n = w * 16 + l;
        const float r = r_ij[(size_t)blk * N_ + n];
        const float c = (r < 5.0f)
            ? 0.5f * (cosf(r * 0.62831853071795865f) + 1.0f)   // pi/5
            : 0.0f;
        s_scale[n] = c * mask[(size_t)blk * N_ + n];
        s_nb[n]    = nbrs[(size_t)blk * N_ + n];
    }

    const short8* fw1B8 = (const short8*)fw1B;
    const short8* fw2B8 = (const short8*)fw2B;

    // ---- GEMM1: h1[n][f] = ssp(f_ij @ fw1 + fb1), A from global fp32 ----
    short8 a1[2];
    {
        const float* base = f_ij + (size_t)blk * (N_ * G_)
                          + (size_t)(w * 16 + c0) * G_ + quad * 8;
        #pragma unroll
        for (int ks = 0; ks < 2; ++ks) {
            const float4 v0 = *(const float4*)(base + ks * 32);
            const float4 v1 = *(const float4*)(base + ks * 32 + 4);
            short8 a;
            a[0] = f2bf(v0.x); a[1] = f2bf(v0.y);
            a[2] = f2bf(v0.z); a[3] = f2bf(v0.w);
            a[4] = f2bf(v1.x); a[5] = f2bf(v1.y);
            a[6] = f2bf(v1.z); a[7] = f2bf(v1.w);
            a1[ks] = a;
        }
    }
    floatx4 acc1[8];
    #pragma unroll
    for (int tf = 0; tf < 8; ++tf) acc1[tf] = (floatx4){0.f, 0.f, 0.f, 0.f};
    #pragma unroll
    for (int ks = 0; ks < 2; ++ks)
        #pragma unroll
        for (int tf = 0; tf < 8; ++tf)
            acc1[tf] = __builtin_amdgcn_mfma_f32_16x16x32_bf16(
                a1[ks], fw1B8[(tf * 2 + ks) * 64 + l], acc1[tf], 0, 0, 0);

    // ssp + bias, store bf16 to LDS with chunk-XOR swizzle
    // physical addr: row*128 + ((chunk ^ (row&15)) * 8) + (col&7)
    #pragma unroll
    for (int tf = 0; tf < 8; ++tf) {
        const float bias  = fb1[tf * 16 + c0];
        const int   chunk = tf * 2 + (c0 >> 3);
        const int   o     = c0 & 7;
        #pragma unroll
        for (int r = 0; r < 4; ++r) {
            const int row_l = quad * 4 + r;            // = row & 15
            const float v = ssp(acc1[tf][r] + bias);
            s_h1[(w * 16 + row_l) * F_ + ((chunk ^ row_l) * 8) + o] = f2bf(v);
        }
    }

    // ---- GEMM2: W[n][f'] = h1 @ fw2 + fb2 ----
    short8 a2[4];
    #pragma unroll
    for (int ks = 0; ks < 4; ++ks)
        a2[ks] = *(const short8*)&s_h1[(w * 16 + c0) * F_
                                       + (((ks * 4 + quad) ^ c0) * 8)];
    floatx4 acc2[8];
    #pragma unroll
    for (int tf = 0; tf < 8; ++tf) acc2[tf] = (floatx4){0.f, 0.f, 0.f, 0.f};
    #pragma unroll
    for (int ks = 0; ks < 4; ++ks)
        #pragma unroll
        for (int tf = 0; tf < 8; ++tf)
            acc2[tf] = __builtin_amdgcn_mfma_f32_16x16x32_bf16(
                a2[ks], fw2B8[(tf * 4 + ks) * 64 + l], acc2[tf], 0, 0, 0);

    // ---- aggregate: part[f'] += (W+fb2) * scale[n] * ypre[nb[n]][f'] ----
    float bias2[8];
    #pragma unroll
    for (int tf = 0; tf < 8; ++tf) bias2[tf] = fb2[tf * 16 + c0];

    float part[8];
    #pragma unroll
    for (int tf = 0; tf < 8; ++tf) part[tf] = 0.0f;
    #pragma unroll
    for (int r = 0; r < 4; ++r) {
        const int n = w * 16 + quad * 4 + r;
        const float sc = s_scale[n];
        if (sc != 0.0f) {
            const unsigned short* yrow =
                ypre + (size_t)(b * A_ + s_nb[n]) * F_ + c0;
            #pragma unroll
            for (int tf = 0; tf < 8; ++tf)
                part[tf] = fmaf((acc2[tf][r] + bias2[tf]) * sc,
                                bf2f(yrow[tf * 16]), part[tf]);
        }
    }

    // butterfly over the 4 quads (rows), then one write per f'
    #pragma unroll
    for (int tf = 0; tf < 8; ++tf) {
        part[tf] += __shfl_xor(part[tf], 16, 64);
        part[tf] += __shfl_xor(part[tf], 32, 64);
    }
    if (l < 16) {
        #pragma unroll
        for (int tf = 0; tf < 8; ++tf)
            s_red[w][tf * 16 + l] = part[tf];
    }
    __syncthreads();

    if (tid < F_)
        s_yf[tid] = s_red[0][tid] + s_red[1][tid] + s_red[2][tid] + s_red[3][tid];
    __syncthreads();

    // ---- f2out epilogue ----
    if (tid < F_) {
        float acc = bf2out[tid];
        #pragma unroll 8
        for (int k = 0; k < F_; ++k)
            acc = fmaf(s_yf[k], wf2out[k * F_ + tid], acc);
        out[(size_t)blk * F_ + tid] = ssp(acc);
    }
}

// ---------------------------------------------------------------------------
extern "C" void kernel_launch(void* const* d_in, const int* in_sizes, int n_in,
                              void* d_out, int out_size, void* d_ws, size_t ws_size,
                              hipStream_t stream) {
    const float* x        = (const float*)d_in[0];
    const float* r_ij     = (const float*)d_in[1];
    const float* f_ij     = (const float*)d_in[2];
    const int*   nbrs     = (const int*)  d_in[3];
    const float* mask     = (const float*)d_in[4];
    const float* fw1      = (const float*)d_in[5];
    const float* fb1      = (const float*)d_in[6];
    const float* fw2      = (const float*)d_in[7];
    const float* fb2      = (const float*)d_in[8];
    const float* w_in2f   = (const float*)d_in[9];
    const float* w_f2out  = (const float*)d_in[10];
    const float* b_f2out  = (const float*)d_in[11];
    float* out = (float*)d_out;

    // workspace layout (shorts): ypre [4096*128] | fw1B [8192] | fw2B [16384]
    unsigned short* ypre = (unsigned short*)d_ws;
    unsigned short* fw1B = ypre + (size_t)B_ * A_ * F_;
    unsigned short* fw2B = fw1B + 8192;

    in2f_kernel<<<B_ * A_ / 2, 256, 0, stream>>>(x, w_in2f, ypre);
    prep_weights<<<(8192 + 16384) / 256, 256, 0, stream>>>(fw1, fw2, fw1B, fw2B);
    cfconv_kernel<<<B_ * A_, 256, 0, stream>>>(
        r_ij, f_ij, nbrs, mask, fb1, fb2,
        ypre, fw1B, fw2B, w_f2out, b_f2out, out);
}

// Round 3
// 163.221 us; speedup vs baseline: 3.1248x; 1.3665x over previous
//
#include <hip/hip_runtime.h>
#include <hip/hip_bf16.h>
#include <math.h>

#define B_ 16
#define A_ 256
#define N_ 64
#define G_ 64
#define F_ 128

typedef __attribute__((ext_vector_type(8))) short short8;
typedef __attribute__((ext_vector_type(4))) float floatx4;

__device__ __forceinline__ float ssp(float x) {
    // shifted softplus via native v_exp_f32 / v_log_f32 (fast intrinsics):
    // ln(1+e^x) - ln2 = max(x,0) + ln(1+e^-|x|) - ln2
    const float t = __expf(-fabsf(x));
    return fmaxf(x, 0.0f) + __logf(1.0f + t) - 0.69314718055994531f;
}
__device__ __forceinline__ short f2bf(float f) {
    union { __hip_bfloat16 h; short s; } u;
    u.h = __float2bfloat16(f);
    return u.s;
}
__device__ __forceinline__ float bf2f(unsigned short u) {
    union { unsigned int i; float f; } v;
    v.i = ((unsigned)u) << 16;
    return v.f;
}

// ---------------------------------------------------------------------------
// Repack weights into MFMA B-fragment order (bf16).
// For a KxF (F=128) weight: frag layout [tf][ks][lane(64)][j(8)],
//   k = ks*32 + (lane>>4)*8 + j,  f = tf*16 + (lane&15)
// fw1: K=64 (2 ks), fw2 / w_in2f / w_f2out: K=128 (4 ks)
__global__ __launch_bounds__(256) void prep_weights(
    const float* __restrict__ fw1, const float* __restrict__ fw2,
    const float* __restrict__ win, const float* __restrict__ wout,
    unsigned short* __restrict__ fw1B, unsigned short* __restrict__ fw2B,
    unsigned short* __restrict__ winB, unsigned short* __restrict__ woutB)
{
    const int idx = blockIdx.x * 256 + threadIdx.x;   // 0 .. 57343
    if (idx < 8192) {
        const int j  = idx & 7;
        const int l  = (idx >> 3) & 63;
        const int ks = (idx >> 9) & 1;
        const int tf = idx >> 10;
        const int g  = ks * 32 + (l >> 4) * 8 + j;
        const int f  = tf * 16 + (l & 15);
        fw1B[idx] = (unsigned short)f2bf(fw1[g * F_ + f]);
    } else {
        const int i2 = (idx - 8192) & 16383;          // index within a 128x128 pack
        const int sel = (idx - 8192) >> 14;           // 0: fw2, 1: win, 2: wout
        const int j  = i2 & 7;
        const int l  = (i2 >> 3) & 63;
        const int ks = (i2 >> 9) & 3;
        const int tf = i2 >> 11;
        const int k  = ks * 32 + (l >> 4) * 8 + j;
        const int f  = tf * 16 + (l & 15);
        const float* src = (sel == 0) ? fw2 : (sel == 1) ? win : wout;
        unsigned short* dst = (sel == 0) ? fw2B : (sel == 1) ? winB : woutB;
        dst[i2] = (unsigned short)f2bf(src[k * F_ + f]);
    }
}

// ---------------------------------------------------------------------------
// C[R,128] = act(A[R,128] @ W + bias). MODE 0: A fp32, no bias/act, C bf16.
//            MODE 1: A bf16, +bias, ssp, C fp32.
// One wave per 16 rows, 4 waves/block -> 64 rows/block.
template<int MODE>
__global__ __launch_bounds__(256) void gemm128_kernel(
    const void* __restrict__ Ain, const unsigned short* __restrict__ WB,
    const float* __restrict__ bias, void* __restrict__ Cout)
{
    const int tid = threadIdx.x;
    const int w = tid >> 6, l = tid & 63, quad = l >> 4, c0 = l & 15;
    const int row = blockIdx.x * 64 + w * 16 + c0;   // A-frag row (m = lane&15)

    short8 a[4];
    if (MODE == 0) {
        const float* A = (const float*)Ain + (size_t)row * F_ + quad * 8;
        #pragma unroll
        for (int ks = 0; ks < 4; ++ks) {
            const float4 v0 = *(const float4*)(A + ks * 32);
            const float4 v1 = *(const float4*)(A + ks * 32 + 4);
            short8 t;
            t[0] = f2bf(v0.x); t[1] = f2bf(v0.y);
            t[2] = f2bf(v0.z); t[3] = f2bf(v0.w);
            t[4] = f2bf(v1.x); t[5] = f2bf(v1.y);
            t[6] = f2bf(v1.z); t[7] = f2bf(v1.w);
            a[ks] = t;
        }
    } else {
        const unsigned short* A = (const unsigned short*)Ain
                                + (size_t)row * F_ + quad * 8;
        #pragma unroll
        for (int ks = 0; ks < 4; ++ks)
            a[ks] = *(const short8*)(A + ks * 32);
    }

    const short8* W8 = (const short8*)WB;
    floatx4 acc[8];
    #pragma unroll
    for (int tf = 0; tf < 8; ++tf) acc[tf] = (floatx4){0.f, 0.f, 0.f, 0.f};
    #pragma unroll
    for (int ks = 0; ks < 4; ++ks)
        #pragma unroll
        for (int tf = 0; tf < 8; ++tf)
            acc[tf] = __builtin_amdgcn_mfma_f32_16x16x32_bf16(
                a[ks], W8[(tf * 4 + ks) * 64 + l], acc[tf], 0, 0, 0);

    // C/D: col = tf*16 + (lane&15), row = (lane>>4)*4 + r
    #pragma unroll
    for (int tf = 0; tf < 8; ++tf) {
        #pragma unroll
        for (int r = 0; r < 4; ++r) {
            const int ro = blockIdx.x * 64 + w * 16 + quad * 4 + r;
            const int co = tf * 16 + c0;
            if (MODE == 0)
                ((unsigned short*)Cout)[(size_t)ro * F_ + co] =
                    (unsigned short)f2bf(acc[tf][r]);
            else
                ((float*)Cout)[(size_t)ro * F_ + co] = ssp(acc[tf][r] + bias[co]);
        }
    }
}

// ---------------------------------------------------------------------------
// One block per (b,a). MFMA filter net + cutoff + gather + aggregate.
// Wave w owns neighbor rows [w*16, w*16+16) end-to-end (no barrier in body).
__global__ __launch_bounds__(256) void cfconv_kernel(
    const float* __restrict__ r_ij, const float* __restrict__ f_ij,
    const int*   __restrict__ nbrs, const float* __restrict__ mask,
    const float* __restrict__ fb1,  const float* __restrict__ fb2,
    const unsigned short* __restrict__ ypre,
    const unsigned short* __restrict__ fw1B,
    const unsigned short* __restrict__ fw2B,
    unsigned short* __restrict__ y_agg)
{
    __shared__ short s_h1[N_ * F_];    // 16 KB, XOR-swizzled 8-elem chunks
    __shared__ float s_scale[N_];
    __shared__ int   s_nb[N_];
    __shared__ float s_red[4][F_];

    const int blk  = blockIdx.x;       // b*A + a
    const int tid  = threadIdx.x;
    const int b    = blk >> 8;         // A = 256
    const int w    = tid >> 6;
    const int l    = tid & 63;
    const int quad = l >> 4;
    const int c0   = l & 15;

    if (l < 16) {
        const int n = w * 16 + l;
        const float r = r_ij[(size_t)blk * N_ + n];
        const float c = (r < 5.0f)
            ? 0.5f * (cosf(r * 0.62831853071795865f) + 1.0f)   // pi/5
            : 0.0f;
        s_scale[n] = c * mask[(size_t)blk * N_ + n];
        s_nb[n]    = nbrs[(size_t)blk * N_ + n];
    }

    const short8* fw1B8 = (const short8*)fw1B;
    const short8* fw2B8 = (const short8*)fw2B;

    // ---- GEMM1: h1 = ssp(f_ij @ fw1 + fb1), A from global fp32 ----
    short8 a1[2];
    {
        const float* base = f_ij + (size_t)blk * (N_ * G_)
                          + (size_t)(w * 16 + c0) * G_ + quad * 8;
        #pragma unroll
        for (int ks = 0; ks < 2; ++ks) {
            const float4 v0 = *(const float4*)(base + ks * 32);
            const float4 v1 = *(const float4*)(base + ks * 32 + 4);
            short8 a;
            a[0] = f2bf(v0.x); a[1] = f2bf(v0.y);
            a[2] = f2bf(v0.z); a[3] = f2bf(v0.w);
            a[4] = f2bf(v1.x); a[5] = f2bf(v1.y);
            a[6] = f2bf(v1.z); a[7] = f2bf(v1.w);
            a1[ks] = a;
        }
    }
    floatx4 acc1[8];
    #pragma unroll
    for (int tf = 0; tf < 8; ++tf) acc1[tf] = (floatx4){0.f, 0.f, 0.f, 0.f};
    #pragma unroll
    for (int ks = 0; ks < 2; ++ks)
        #pragma unroll
        for (int tf = 0; tf < 8; ++tf)
            acc1[tf] = __builtin_amdgcn_mfma_f32_16x16x32_bf16(
                a1[ks], fw1B8[(tf * 2 + ks) * 64 + l], acc1[tf], 0, 0, 0);

    // ssp + bias, store bf16 to LDS with chunk-XOR swizzle
    #pragma unroll
    for (int tf = 0; tf < 8; ++tf) {
        const float bias  = fb1[tf * 16 + c0];
        const int   chunk = tf * 2 + (c0 >> 3);
        const int   o     = c0 & 7;
        #pragma unroll
        for (int r = 0; r < 4; ++r) {
            const int row_l = quad * 4 + r;
            const float v = ssp(acc1[tf][r] + bias);
            s_h1[(w * 16 + row_l) * F_ + ((chunk ^ row_l) * 8) + o] = f2bf(v);
        }
    }

    // ---- GEMM2: W = h1 @ fw2 + fb2 ----
    short8 a2[4];
    #pragma unroll
    for (int ks = 0; ks < 4; ++ks)
        a2[ks] = *(const short8*)&s_h1[(w * 16 + c0) * F_
                                       + (((ks * 4 + quad) ^ c0) * 8)];
    floatx4 acc2[8];
    #pragma unroll
    for (int tf = 0; tf < 8; ++tf) acc2[tf] = (floatx4){0.f, 0.f, 0.f, 0.f};
    #pragma unroll
    for (int ks = 0; ks < 4; ++ks)
        #pragma unroll
        for (int tf = 0; tf < 8; ++tf)
            acc2[tf] = __builtin_amdgcn_mfma_f32_16x16x32_bf16(
                a2[ks], fw2B8[(tf * 4 + ks) * 64 + l], acc2[tf], 0, 0, 0);

    // ---- aggregate ----
    float bias2[8];
    #pragma unroll
    for (int tf = 0; tf < 8; ++tf) bias2[tf] = fb2[tf * 16 + c0];

    float part[8];
    #pragma unroll
    for (int tf = 0; tf < 8; ++tf) part[tf] = 0.0f;
    #pragma unroll
    for (int r = 0; r < 4; ++r) {
        const int n = w * 16 + quad * 4 + r;
        const float sc = s_scale[n];
        if (sc != 0.0f) {
            const unsigned short* yrow =
                ypre + (size_t)(b * A_ + s_nb[n]) * F_ + c0;
            #pragma unroll
            for (int tf = 0; tf < 8; ++tf)
                part[tf] = fmaf((acc2[tf][r] + bias2[tf]) * sc,
                                bf2f(yrow[tf * 16]), part[tf]);
        }
    }

    #pragma unroll
    for (int tf = 0; tf < 8; ++tf) {
        part[tf] += __shfl_xor(part[tf], 16, 64);
        part[tf] += __shfl_xor(part[tf], 32, 64);
    }
    if (l < 16) {
        #pragma unroll
        for (int tf = 0; tf < 8; ++tf)
            s_red[w][tf * 16 + l] = part[tf];
    }
    __syncthreads();

    if (tid < F_) {
        const float v = s_red[0][tid] + s_red[1][tid]
                      + s_red[2][tid] + s_red[3][tid];
        y_agg[(size_t)blk * F_ + tid] = (unsigned short)f2bf(v);
    }
}

// ---------------------------------------------------------------------------
extern "C" void kernel_launch(void* const* d_in, const int* in_sizes, int n_in,
                              void* d_out, int out_size, void* d_ws, size_t ws_size,
                              hipStream_t stream) {
    const float* x        = (const float*)d_in[0];
    const float* r_ij     = (const float*)d_in[1];
    const float* f_ij     = (const float*)d_in[2];
    const int*   nbrs     = (const int*)  d_in[3];
    const float* mask     = (const float*)d_in[4];
    const float* fw1      = (const float*)d_in[5];
    const float* fb1      = (const float*)d_in[6];
    const float* fw2      = (const float*)d_in[7];
    const float* fb2      = (const float*)d_in[8];
    const float* w_in2f   = (const float*)d_in[9];
    const float* w_f2out  = (const float*)d_in[10];
    const float* b_f2out  = (const float*)d_in[11];
    float* out = (float*)d_out;

    // ws layout (shorts): ypre | fw1B | fw2B | winB | woutB | y_agg
    unsigned short* ypre  = (unsigned short*)d_ws;
    unsigned short* fw1B  = ypre  + (size_t)B_ * A_ * F_;   // 524288
    unsigned short* fw2B  = fw1B  + 8192;
    unsigned short* winB  = fw2B  + 16384;
    unsigned short* woutB = winB  + 16384;
    unsigned short* y_agg = woutB + 16384;                  // 524288 shorts

    prep_weights<<<(8192 + 3 * 16384) / 256, 256, 0, stream>>>(
        fw1, fw2, w_in2f, w_f2out, fw1B, fw2B, winB, woutB);
    gemm128_kernel<0><<<B_ * A_ / 64, 256, 0, stream>>>(x, winB, nullptr, ypre);
    cfconv_kernel<<<B_ * A_, 256, 0, stream>>>(
        r_ij, f_ij, nbrs, mask, fb1, fb2, ypre, fw1B, fw2B, y_agg);
    gemm128_kernel<1><<<B_ * A_ / 64, 256, 0, stream>>>(y_agg, woutB, b_f2out, out);
}